// Round 6
// baseline (136.706 us; speedup 1.0000x reference)
//
#include <hip/hip_runtime.h>
#include <math.h>

#define LSEQ 1024
#define DDIM 256
#define NC 64          // chunks along L (scan pipeline)
#define CHUNK 16
#define NCS 16         // chunks along L (stats)
#define CHS 64
#define CSTR 144       // packed coef row stride (floats)
#define ROWS 8         // row tile for projection kernels
#define PI_F 3.14159265358979323846f
#define F(l) ((l) + ((l) >> 5))   // bank-padded LDS index

// coef row layout (per b,l), 36 planes = 16 bank + 4 joint + 16 pos:
// [0:36) Kre  [36:72) Kim  [72:108) Qre  [108:144) Qim
// (Q weights folded: bank 0.025, joint 0.1, pos 0.5. Gate NOT folded.)

// ---------------- K1: phases + joint phases + pos phases + V (8-row tile) ----------------
__global__ void k_phases(const float* __restrict__ x, const float* __restrict__ kp,
                         const float* __restrict__ qp, const float* __restrict__ vp,
                         const float* __restrict__ pos_freqs,
                         float* __restrict__ coef, float* __restrict__ V) {
    int r0 = blockIdx.x * ROWS;     // over B*LSEQ
    int t  = threadIdx.x;
    __shared__ __align__(16) float xs[ROWS][DDIM];
    __shared__ float phi[ROWS][32];
    {
        const float4* src = (const float4*)(x + (size_t)r0 * DDIM);
        float4* dst = (float4*)&xs[0][0];
        #pragma unroll
        for (int i = t; i < ROWS * DDIM / 4; i += 256) dst[i] = src[i];
    }
    __syncthreads();
    {   // 256 threads: one phase-dot each (8 rows x 32 projections)
        int r = t >> 5, j5 = t & 31;
        const float* W = (j5 < 16) ? kp : qp;
        int j = j5 & 15;
        float acc = 0.f;
        #pragma unroll 8
        for (int i = 0; i < DDIM; ++i) acc += xs[r][i] * W[i * 16 + j];
        float ph = tanhf(acc) * PI_F;
        phi[r][j5] = ph;
        float s, c; sincosf(ph, &s, &c);   // SIN FIRST
        float* crow = coef + (size_t)(r0 + r) * CSTR;
        if (j5 < 16) { crow[j] = c;               crow[36 + j] = s; }
        else         { crow[72 + j] = 0.025f * c; crow[108 + j] = 0.025f * s; }
    }
    __syncthreads();
    if (t < ROWS * 8) {    // joint phases: 8 rows x 8 slots
        int r = t >> 3, k = t & 7, p = k & 3;
        const float* p4 = phi[r] + ((k < 4) ? 0 : 16);
        float sum = p4[p] + p4[4 + p] + p4[8 + p] + p4[12 + p];
        float s, c; sincosf(sum, &s, &c);
        float* crow = coef + (size_t)(r0 + r) * CSTR;
        if (k < 4) { crow[16 + p] = c;        crow[52 + p] = s; }
        else       { crow[88 + p] = 0.1f * c; crow[124 + p] = 0.1f * s; }
    }
    if (t >= 64 && t < 64 + ROWS * 16) {  // positional phases: 8 rows x 16 planes
        int u = t - 64, r = u >> 4, pl = u & 15;
        int l = (r0 + r) & (LSEQ - 1);
        float a = (((float)l * pos_freqs[pl]) * 2.0f) * PI_F;
        float s, c; sincosf(a, &s, &c);
        float* crow = coef + (size_t)(r0 + r) * CSTR;
        crow[20 + pl] = c;        crow[56 + pl] = s;
        crow[92 + pl] = 0.5f * c; crow[128 + pl] = 0.5f * s;
    }
    // V = x @ value_proj: 8 rows per thread-column, weight column loaded once
    float acc[ROWS];
    #pragma unroll
    for (int r = 0; r < ROWS; ++r) acc[r] = 0.f;
    for (int i = 0; i < DDIM; ++i) {
        float wv = vp[i * DDIM + t];
        #pragma unroll
        for (int r = 0; r < ROWS; ++r) acc[r] += xs[r][i] * wv;
    }
    #pragma unroll
    for (int r = 0; r < ROWS; ++r) V[(size_t)(r0 + r) * DDIM + t] = acc[r];
}

// ---------------- K2a: per-chunk sums for running stats ----------------
__global__ void k_stats1(const float* __restrict__ x, float* __restrict__ Ssum,
                         float* __restrict__ Ssq) {
    int c = blockIdx.x, b = blockIdx.z, d = blockIdx.y * 64 + threadIdx.x;
    float s1 = 0.f, s2 = 0.f;
    for (int l = c * CHS; l < c * CHS + CHS; ++l) {
        float v = x[((size_t)(b * LSEQ + l)) * DDIM + d];
        s1 += v; s2 += v * v;
    }
    Ssum[(b * NCS + c) * DDIM + d] = s1;
    Ssq [(b * NCS + c) * DDIM + d] = s2;
}

// ---------------- K2b: running mean / std within chunk ----------------
__global__ void k_stats2(const float* __restrict__ x, const float* __restrict__ Ssum,
                         const float* __restrict__ Ssq, float* __restrict__ rmean,
                         float* __restrict__ rstd) {
    int c = blockIdx.x, b = blockIdx.z, d = blockIdx.y * 64 + threadIdx.x;
    float cs = 0.f, css = 0.f;
    for (int cc = 0; cc < c; ++cc) {
        cs  += Ssum[(b * NCS + cc) * DDIM + d];
        css += Ssq [(b * NCS + cc) * DDIM + d];
    }
    for (int l = c * CHS; l < c * CHS + CHS; ++l) {
        size_t idx = ((size_t)(b * LSEQ + l)) * DDIM + d;
        float v = x[idx];
        cs += v; css += v * v;
        float inv = 1.0f / (float)(l + 1);
        float m = cs * inv;
        float var = css * inv - m * m;
        rmean[idx] = m;
        rstd[idx] = sqrtf(fmaxf(var, 1e-8f));
    }
}

// ---------------- K3: LTM phases + persistent readout (8-row tile) ----------------
__global__ void k_ltm(const float* __restrict__ x, const float* __restrict__ rmean,
                      const float* __restrict__ rstd, const float* __restrict__ lkp,
                      const float* __restrict__ bre, const float* __restrict__ bim,
                      float* __restrict__ pers) {
    int r0 = blockIdx.x * ROWS;
    int t = threadIdx.x;
    __shared__ float ins[ROWS][768];      // 24 KB
    __shared__ float part[ROWS][2][16];
    __shared__ float csn[ROWS][2][16];
    for (int i = t; i < ROWS * DDIM; i += 256) {
        int r = i >> 8, k = i & 255;
        size_t row = (size_t)(r0 + r) * DDIM;
        ins[r][k]       = x[row + k];
        ins[r][256 + k] = rmean[row + k];
        ins[r][512 + k] = rstd[row + k];
    }
    __syncthreads();
    {   // 768-dot split in halves: t = r*32 + h*16 + j
        int r = t >> 5, h = (t >> 4) & 1, j = t & 15;
        int i0 = h * 384;
        float acc = 0.f;
        #pragma unroll 8
        for (int i = 0; i < 384; ++i) acc += ins[r][i0 + i] * lkp[(i0 + i) * 16 + j];
        part[r][h][j] = acc;
    }
    __syncthreads();
    if (t < ROWS * 16) {
        int r = t >> 4, j = t & 15;
        float th = tanhf(part[r][0][j] + part[r][1][j]) * PI_F;
        float s, c; sincosf(th, &s, &c);   // SIN FIRST
        csn[r][0][j] = c; csn[r][1][j] = s;
    }
    __syncthreads();
    float acc[ROWS];
    #pragma unroll
    for (int r = 0; r < ROWS; ++r) acc[r] = 0.f;
    #pragma unroll
    for (int pl = 0; pl < 16; ++pl) {
        float br = bre[pl * DDIM + t], bi = bim[pl * DDIM + t];
        #pragma unroll
        for (int r = 0; r < ROWS; ++r)
            acc[r] += br * csn[r][0][pl] + bi * csn[r][1][pl];
    }
    #pragma unroll
    for (int r = 0; r < ROWS; ++r) pers[(size_t)(r0 + r) * DDIM + t] = acc[r];
}

// ---------------- K4: write gate via parallel prefix scan ----------------
__global__ void k_gate(const float* __restrict__ coef, float* __restrict__ gate) {
    int b = blockIdx.x, t = threadIdx.x;
    __shared__ float sm[8][1056];   // 8 channels, padded
    __shared__ float part[8][33];
    for (int idx = t; idx < LSEQ * 8; idx += 256) {
        int l = idx >> 3, k = idx & 7;
        sm[k][F(l)] = coef[((size_t)(b * LSEQ + l)) * CSTR + ((k < 4) ? (16 + k) : (48 + k))];
    }
    __syncthreads();
    int g = t >> 5, r = t & 31;
    {   // local sums of 32-element segments
        float s = 0.f;
        int base = r * 33;    // F(r*32+i) = r*33+i
        #pragma unroll
        for (int i = 0; i < 32; ++i) s += sm[g][base + i];
        part[g][r] = s;
    }
    __syncthreads();
    if (r == 0) {
        float run = 0.f;
        #pragma unroll
        for (int i = 0; i < 32; ++i) { float tmp = part[g][i]; part[g][i] = run; run += tmp; }
    }
    __syncthreads();
    {   // replay: replace with exclusive prefix
        float run = part[g][r];
        int base = r * 33;
        #pragma unroll
        for (int i = 0; i < 32; ++i) {
            float tmp = sm[g][base + i];
            sm[g][base + i] = run;
            run += tmp;
        }
    }
    __syncthreads();
    for (int l = t; l < LSEQ; l += 256) {
        float m = 0.f;
        int fl = F(l);
        #pragma unroll
        for (int p = 0; p < 4; ++p) {
            float ar = sm[p][fl], ai = sm[4 + p][fl];
            m += sqrtf(ar * ar + ai * ai);
        }
        m *= 0.25f;
        float nr = m / sqrtf(fmaxf((float)l, 1.0f));
        float sup = 0.5f * (1.0f - tanhf(5.0f * (nr - 0.3f)));
        gate[b * LSEQ + l] = 1.0f / (1.0f + expf(-5.0f * (sup - 0.5f)));
    }
}

// ---------------- K5a: per-chunk plane sums (uniform scalar coef reads) ----------------
__global__ void k_chunksum(const float* __restrict__ coef, const float* __restrict__ V,
                           const float* __restrict__ gate, float* __restrict__ S) {
    int c = blockIdx.x, b = blockIdx.z, d = blockIdx.y * 64 + threadIdx.x;
    const float* cr0 = coef + ((size_t)(b * LSEQ + c * CHUNK)) * CSTR;
    const float* gt  = gate + b * LSEQ + c * CHUNK;
    float vbuf[CHUNK];
    #pragma unroll
    for (int l = 0; l < CHUNK; ++l)
        vbuf[l] = V[((size_t)(b * LSEQ + c * CHUNK + l)) * DDIM + d];
    float sre[36], sim[36];
    #pragma unroll
    for (int i = 0; i < 36; ++i) { sre[i] = 0.f; sim[i] = 0.f; }
    #pragma unroll
    for (int l = 0; l < CHUNK; ++l) {
        const float* cr = cr0 + l * CSTR;   // block-uniform -> s_load
        float g = gt[l];
        float v = vbuf[l];
        float vg = v * g;
        #pragma unroll
        for (int q = 0; q < 9; ++q) {
            float val = (q <= 4) ? vg : v;   // planes 0-19 gated, 20-35 ungated
            #pragma unroll
            for (int j = 0; j < 4; ++j) {
                sre[4*q+j] += cr[4*q+j] * val;
                sim[4*q+j] += cr[36 + 4*q+j] * val;
            }
        }
    }
    size_t base = ((size_t)(b * NC + c) * 72) * DDIM + d;
    #pragma unroll
    for (int i = 0; i < 36; ++i) {
        S[base + (size_t)i * DDIM] = sre[i];
        S[base + (size_t)(36 + i) * DDIM] = sim[i];
    }
}

// ---------------- K5b: exclusive prefix over chunks (register-batched) ----------------
__global__ void k_prefix(float* __restrict__ S) {
    int q = blockIdx.x, b = blockIdx.z, d = blockIdx.y * 64 + threadIdx.x;
    float acc = 0.f;
    for (int batch = 0; batch < NC / 32; ++batch) {
        float r[32];
        #pragma unroll
        for (int i = 0; i < 32; ++i)
            r[i] = S[((size_t)(b * NC + batch * 32 + i) * 72 + q) * DDIM + d];
        #pragma unroll
        for (int i = 0; i < 32; ++i) { float tmp = r[i]; r[i] = acc; acc += tmp; }
        #pragma unroll
        for (int i = 0; i < 32; ++i)
            S[((size_t)(b * NC + batch * 32 + i) * 72 + q) * DDIM + d] = r[i];
    }
}

// ---------------- K5c: within-chunk scan + retrieval (+0.125*pers, in place) ----------------
__global__ void k_scan(const float* __restrict__ coef, const float* __restrict__ V,
                       const float* __restrict__ gate, const float* __restrict__ S,
                       float* __restrict__ tp) {
    int c = blockIdx.x, b = blockIdx.z, d = blockIdx.y * 64 + threadIdx.x;
    const float* cr0 = coef + ((size_t)(b * LSEQ + c * CHUNK)) * CSTR;
    const float* gt  = gate + b * LSEQ + c * CHUNK;
    float vbuf[CHUNK], tpb[CHUNK];
    #pragma unroll
    for (int l = 0; l < CHUNK; ++l) {
        size_t idx = ((size_t)(b * LSEQ + c * CHUNK + l)) * DDIM + d;
        vbuf[l] = V[idx];
        tpb[l]  = tp[idx];
    }
    float sre[36], sim[36];
    size_t base = ((size_t)(b * NC + c) * 72) * DDIM + d;
    #pragma unroll
    for (int i = 0; i < 36; ++i) {
        sre[i] = S[base + (size_t)i * DDIM];
        sim[i] = S[base + (size_t)(36 + i) * DDIM];
    }
    #pragma unroll
    for (int l = 0; l < CHUNK; ++l) {
        const float* cr = cr0 + l * CSTR;   // block-uniform -> s_load
        float g = gt[l];
        float v = vbuf[l];
        float vg = v * g;
        float rx = 0.f, ry = 0.f, rz = 0.f, rw = 0.f;
        #pragma unroll
        for (int q = 0; q < 9; ++q) {
            float val = (q <= 4) ? vg : v;
            sre[4*q+0] += cr[4*q+0] * val; rx += cr[72+4*q+0] * sre[4*q+0];
            sre[4*q+1] += cr[4*q+1] * val; ry += cr[72+4*q+1] * sre[4*q+1];
            sre[4*q+2] += cr[4*q+2] * val; rz += cr[72+4*q+2] * sre[4*q+2];
            sre[4*q+3] += cr[4*q+3] * val; rw += cr[72+4*q+3] * sre[4*q+3];
            sim[4*q+0] += cr[36+4*q+0] * val; rx += cr[108+4*q+0] * sim[4*q+0];
            sim[4*q+1] += cr[36+4*q+1] * val; ry += cr[108+4*q+1] * sim[4*q+1];
            sim[4*q+2] += cr[36+4*q+2] * val; rz += cr[108+4*q+2] * sim[4*q+2];
            sim[4*q+3] += cr[36+4*q+3] * val; rw += cr[108+4*q+3] * sim[4*q+3];
        }
        size_t oidx = ((size_t)(b * LSEQ + c * CHUNK + l)) * DDIM + d;
        tp[oidx] = ((rx + ry) + (rz + rw)) + 0.125f * tpb[l];  // tp aliases pers
    }
}

// ---------------- K6: epilogue: (total/norm) @ out_proj + x (8-row tile) ----------------
__global__ void k_out(const float* __restrict__ x, const float* __restrict__ tp,
                      const float* __restrict__ op, float* __restrict__ out) {
    int r0 = blockIdx.x * ROWS;
    int t = threadIdx.x;
    __shared__ __align__(16) float ts[ROWS][DDIM];
    for (int i = t; i < ROWS * DDIM; i += 256) {
        int r = i >> 8, k = i & 255;
        int l = (r0 + r) & (LSEQ - 1);
        float invn = 1.0f / (2.0f * sqrtf((float)(l + 1)));
        ts[r][k] = tp[(size_t)(r0 + r) * DDIM + k] * invn;
    }
    __syncthreads();
    float acc[ROWS];
    #pragma unroll
    for (int r = 0; r < ROWS; ++r) acc[r] = 0.f;
    for (int i = 0; i < DDIM; ++i) {
        float wv = op[i * DDIM + t];
        #pragma unroll
        for (int r = 0; r < ROWS; ++r) acc[r] += ts[r][i] * wv;
    }
    #pragma unroll
    for (int r = 0; r < ROWS; ++r)
        out[(size_t)(r0 + r) * DDIM + t] = x[(size_t)(r0 + r) * DDIM + t] + acc[r];
}

extern "C" void kernel_launch(void* const* d_in, const int* in_sizes, int n_in,
                              void* d_out, int out_size, void* d_ws, size_t ws_size,
                              hipStream_t stream) {
    const float* x   = (const float*)d_in[0];
    const float* kp  = (const float*)d_in[1];
    const float* qp  = (const float*)d_in[2];
    const float* vp  = (const float*)d_in[3];
    const float* op  = (const float*)d_in[4];
    const float* lkp = (const float*)d_in[5];
    const float* pf  = (const float*)d_in[7];
    const float* bre = (const float*)d_in[10];
    const float* bim = (const float*)d_in[11];
    float* out = (float*)d_out;

    const int B = 2;
    float* w = (float*)d_ws;
    size_t off = 0;
    float* coef  = w + off; off += (size_t)B * LSEQ * CSTR;       // 294912
    float* V     = w + off; off += (size_t)B * LSEQ * DDIM;       // 524288
    float* pers  = w + off; off += (size_t)B * LSEQ * DDIM;       // aliased as tcp
    float* gate  = w + off; off += (size_t)B * LSEQ;
    float* Ssum  = w + off; off += (size_t)B * NCS * DDIM;
    float* Ssq   = w + off; off += (size_t)B * NCS * DDIM;
    // X region: rmean+rstd (dead after k_ltm) aliased with S (written by k_chunksum)
    float* rmean = w + off;
    float* rstd  = w + off + (size_t)B * LSEQ * DDIM;
    float* S     = w + off; off += (size_t)B * NC * 72 * DDIM;    // 2359296
    // total ~14.2 MB (ws is 256 MiB per profile fills)

    k_phases<<<dim3(B * LSEQ / ROWS), dim3(256), 0, stream>>>(x, kp, qp, vp, pf, coef, V);
    k_gate<<<dim3(B), dim3(256), 0, stream>>>(coef, gate);
    k_stats1<<<dim3(NCS, 4, B), dim3(64), 0, stream>>>(x, Ssum, Ssq);
    k_stats2<<<dim3(NCS, 4, B), dim3(64), 0, stream>>>(x, Ssum, Ssq, rmean, rstd);
    k_ltm<<<dim3(B * LSEQ / ROWS), dim3(256), 0, stream>>>(x, rmean, rstd, lkp, bre, bim, pers);
    k_chunksum<<<dim3(NC, 4, B), dim3(64), 0, stream>>>(coef, V, gate, S);
    k_prefix<<<dim3(72, 4, B), dim3(64), 0, stream>>>(S);
    k_scan<<<dim3(NC, 4, B), dim3(64), 0, stream>>>(coef, V, gate, S, pers);
    k_out<<<dim3(B * LSEQ / ROWS), dim3(256), 0, stream>>>(x, pers, op, out);
}

// Round 7
// 124.538 us; speedup vs baseline: 1.0977x; 1.0977x over previous
//
#include <hip/hip_runtime.h>
#include <math.h>

#define LSEQ 1024
#define DDIM 256
#define NC 64          // chunks along L (scan pipeline)
#define CHUNK 16
#define NCS 16         // chunks along L (stats)
#define CHS 64
#define CSTR 144       // packed coef row stride (floats)
#define ROWS 2         // row tile for projection kernels (16 waves/CU at grid 1024)
#define PI_F 3.14159265358979323846f
#define F(l) ((l) + ((l) >> 5))   // bank-padded LDS index

// coef row layout (per b,l), 36 planes = 16 bank + 4 joint + 16 pos:
// [0:36) Kre  [36:72) Kim  [72:108) Qre  [108:144) Qim
// (Q weights folded: bank 0.025, joint 0.1, pos 0.5. Gate NOT folded.)

// ---------------- K1: phases + joint phases + pos phases + V (2-row tile) ----------------
__global__ void k_phases(const float* __restrict__ x, const float* __restrict__ kp,
                         const float* __restrict__ qp, const float* __restrict__ vp,
                         const float* __restrict__ pos_freqs,
                         float* __restrict__ coef, float* __restrict__ V) {
    int r0 = blockIdx.x * ROWS;     // over B*LSEQ
    int t  = threadIdx.x;
    __shared__ __align__(16) float xs[ROWS][DDIM];
    __shared__ float part[ROWS][32][5];
    __shared__ float phi[ROWS][32];
    {
        const float4* src = (const float4*)(x + (size_t)r0 * DDIM);
        float4* dst = (float4*)&xs[0][0];
        if (t < ROWS * DDIM / 4) dst[t] = src[t];
    }
    __syncthreads();
    {   // 64 phase-dots x 4-way i-split = 256 threads
        int r = t >> 7, rem = t & 127, j5 = rem >> 2, s = rem & 3;
        const float* W = (j5 < 16) ? kp : qp;
        int j = j5 & 15;
        int i0 = s * 64;
        float acc = 0.f;
        #pragma unroll 8
        for (int i = 0; i < 64; ++i) acc += xs[r][i0 + i] * W[(i0 + i) * 16 + j];
        part[r][j5][s] = acc;
    }
    __syncthreads();
    if (t < ROWS * 32) {
        int r = t >> 5, j5 = t & 31;
        float ph = tanhf(part[r][j5][0] + part[r][j5][1]
                       + part[r][j5][2] + part[r][j5][3]) * PI_F;
        phi[r][j5] = ph;
        float s, c; sincosf(ph, &s, &c);   // SIN FIRST
        int j = j5 & 15;
        float* crow = coef + (size_t)(r0 + r) * CSTR;
        if (j5 < 16) { crow[j] = c;               crow[36 + j] = s; }
        else         { crow[72 + j] = 0.025f * c; crow[108 + j] = 0.025f * s; }
    }
    __syncthreads();
    if (t < ROWS * 8) {    // joint phases: 2 rows x 8 slots
        int r = t >> 3, k = t & 7, p = k & 3;
        const float* p4 = phi[r] + ((k < 4) ? 0 : 16);
        float sum = p4[p] + p4[4 + p] + p4[8 + p] + p4[12 + p];
        float s, c; sincosf(sum, &s, &c);
        float* crow = coef + (size_t)(r0 + r) * CSTR;
        if (k < 4) { crow[16 + p] = c;        crow[52 + p] = s; }
        else       { crow[88 + p] = 0.1f * c; crow[124 + p] = 0.1f * s; }
    }
    if (t >= 64 && t < 64 + ROWS * 16) {  // positional phases: 2 rows x 16 planes
        int u = t - 64, r = u >> 4, pl = u & 15;
        int l = (r0 + r) & (LSEQ - 1);
        float a = (((float)l * pos_freqs[pl]) * 2.0f) * PI_F;
        float s, c; sincosf(a, &s, &c);
        float* crow = coef + (size_t)(r0 + r) * CSTR;
        crow[20 + pl] = c;        crow[56 + pl] = s;
        crow[92 + pl] = 0.5f * c; crow[128 + pl] = 0.5f * s;
    }
    // V = x @ value_proj: 2 rows per thread-column, float4 LDS reads
    float a0 = 0.f, a1 = 0.f;
    const float4* x40 = (const float4*)&xs[0][0];
    const float4* x41 = (const float4*)&xs[1][0];
    #pragma unroll 4
    for (int i4 = 0; i4 < DDIM / 4; ++i4) {
        float4 v0 = x40[i4], v1 = x41[i4];
        float w0 = vp[(4*i4+0) * DDIM + t];
        float w1 = vp[(4*i4+1) * DDIM + t];
        float w2 = vp[(4*i4+2) * DDIM + t];
        float w3 = vp[(4*i4+3) * DDIM + t];
        a0 += v0.x * w0 + v0.y * w1 + v0.z * w2 + v0.w * w3;
        a1 += v1.x * w0 + v1.y * w1 + v1.z * w2 + v1.w * w3;
    }
    V[(size_t)(r0 + 0) * DDIM + t] = a0;
    V[(size_t)(r0 + 1) * DDIM + t] = a1;
}

// ---------------- K2a: per-chunk sums for running stats ----------------
__global__ void k_stats1(const float* __restrict__ x, float* __restrict__ Ssum,
                         float* __restrict__ Ssq) {
    int c = blockIdx.x, b = blockIdx.z, d = blockIdx.y * 64 + threadIdx.x;
    float s1 = 0.f, s2 = 0.f;
    for (int l = c * CHS; l < c * CHS + CHS; ++l) {
        float v = x[((size_t)(b * LSEQ + l)) * DDIM + d];
        s1 += v; s2 += v * v;
    }
    Ssum[(b * NCS + c) * DDIM + d] = s1;
    Ssq [(b * NCS + c) * DDIM + d] = s2;
}

// ---------------- K2b: running mean / std within chunk ----------------
__global__ void k_stats2(const float* __restrict__ x, const float* __restrict__ Ssum,
                         const float* __restrict__ Ssq, float* __restrict__ rmean,
                         float* __restrict__ rstd) {
    int c = blockIdx.x, b = blockIdx.z, d = blockIdx.y * 64 + threadIdx.x;
    float cs = 0.f, css = 0.f;
    for (int cc = 0; cc < c; ++cc) {
        cs  += Ssum[(b * NCS + cc) * DDIM + d];
        css += Ssq [(b * NCS + cc) * DDIM + d];
    }
    for (int l = c * CHS; l < c * CHS + CHS; ++l) {
        size_t idx = ((size_t)(b * LSEQ + l)) * DDIM + d;
        float v = x[idx];
        cs += v; css += v * v;
        float inv = 1.0f / (float)(l + 1);
        float m = cs * inv;
        float var = css * inv - m * m;
        rmean[idx] = m;
        rstd[idx] = sqrtf(fmaxf(var, 1e-8f));
    }
}

// ---------------- K3: LTM phases + persistent readout (2-row tile) ----------------
__global__ void k_ltm(const float* __restrict__ x, const float* __restrict__ rmean,
                      const float* __restrict__ rstd, const float* __restrict__ lkp,
                      const float* __restrict__ bre, const float* __restrict__ bim,
                      float* __restrict__ pers) {
    int r0 = blockIdx.x * ROWS;
    int t = threadIdx.x;
    __shared__ float ins[ROWS][768];
    __shared__ float part[ROWS][16][9];
    __shared__ float csn[ROWS][2][16];
    {
        size_t row0 = (size_t)r0 * DDIM, row1 = (size_t)(r0 + 1) * DDIM;
        ins[0][t]       = x[row0 + t];
        ins[0][256 + t] = rmean[row0 + t];
        ins[0][512 + t] = rstd[row0 + t];
        ins[1][t]       = x[row1 + t];
        ins[1][256 + t] = rmean[row1 + t];
        ins[1][512 + t] = rstd[row1 + t];
    }
    __syncthreads();
    {   // 32 dots (2 rows x 16 outs) x 8-way split of 96
        int r = t >> 7, rem = t & 127, j = rem >> 3, h = rem & 7;
        int i0 = h * 96;
        float acc = 0.f;
        #pragma unroll 8
        for (int i = 0; i < 96; ++i) acc += ins[r][i0 + i] * lkp[(i0 + i) * 16 + j];
        part[r][j][h] = acc;
    }
    __syncthreads();
    if (t < ROWS * 16) {
        int r = t >> 4, j = t & 15;
        float acc = 0.f;
        #pragma unroll
        for (int h = 0; h < 8; ++h) acc += part[r][j][h];
        float th = tanhf(acc) * PI_F;
        float s, c; sincosf(th, &s, &c);   // SIN FIRST
        csn[r][0][j] = c; csn[r][1][j] = s;
    }
    __syncthreads();
    float a0 = 0.f, a1 = 0.f;
    #pragma unroll
    for (int pl = 0; pl < 16; ++pl) {
        float br = bre[pl * DDIM + t], bi = bim[pl * DDIM + t];
        a0 += br * csn[0][0][pl] + bi * csn[0][1][pl];
        a1 += br * csn[1][0][pl] + bi * csn[1][1][pl];
    }
    pers[(size_t)(r0 + 0) * DDIM + t] = a0;
    pers[(size_t)(r0 + 1) * DDIM + t] = a1;
}

// ---------------- K4: write gate via parallel prefix scan ----------------
__global__ void k_gate(const float* __restrict__ coef, float* __restrict__ gate) {
    int b = blockIdx.x, t = threadIdx.x;
    __shared__ float sm[8][1056];   // 8 channels, padded
    __shared__ float part[8][33];
    for (int idx = t; idx < LSEQ * 8; idx += 256) {
        int l = idx >> 3, k = idx & 7;
        sm[k][F(l)] = coef[((size_t)(b * LSEQ + l)) * CSTR + ((k < 4) ? (16 + k) : (48 + k))];
    }
    __syncthreads();
    int g = t >> 5, r = t & 31;
    {
        float s = 0.f;
        int base = r * 33;
        #pragma unroll
        for (int i = 0; i < 32; ++i) s += sm[g][base + i];
        part[g][r] = s;
    }
    __syncthreads();
    if (r == 0) {
        float run = 0.f;
        #pragma unroll
        for (int i = 0; i < 32; ++i) { float tmp = part[g][i]; part[g][i] = run; run += tmp; }
    }
    __syncthreads();
    {
        float run = part[g][r];
        int base = r * 33;
        #pragma unroll
        for (int i = 0; i < 32; ++i) {
            float tmp = sm[g][base + i];
            sm[g][base + i] = run;
            run += tmp;
        }
    }
    __syncthreads();
    for (int l = t; l < LSEQ; l += 256) {
        float m = 0.f;
        int fl = F(l);
        #pragma unroll
        for (int p = 0; p < 4; ++p) {
            float ar = sm[p][fl], ai = sm[4 + p][fl];
            m += sqrtf(ar * ar + ai * ai);
        }
        m *= 0.25f;
        float nr = m / sqrtf(fmaxf((float)l, 1.0f));
        float sup = 0.5f * (1.0f - tanhf(5.0f * (nr - 0.3f)));
        gate[b * LSEQ + l] = 1.0f / (1.0f + expf(-5.0f * (sup - 0.5f)));
    }
}

// ---------------- K5a: per-chunk plane sums (uniform scalar coef reads) ----------------
__global__ void k_chunksum(const float* __restrict__ coef, const float* __restrict__ V,
                           const float* __restrict__ gate, float* __restrict__ S) {
    int c = blockIdx.x, b = blockIdx.z, d = blockIdx.y * 64 + threadIdx.x;
    const float* cr0 = coef + ((size_t)(b * LSEQ + c * CHUNK)) * CSTR;
    const float* gt  = gate + b * LSEQ + c * CHUNK;
    float vbuf[CHUNK];
    #pragma unroll
    for (int l = 0; l < CHUNK; ++l)
        vbuf[l] = V[((size_t)(b * LSEQ + c * CHUNK + l)) * DDIM + d];
    float sre[36], sim[36];
    #pragma unroll
    for (int i = 0; i < 36; ++i) { sre[i] = 0.f; sim[i] = 0.f; }
    #pragma unroll
    for (int l = 0; l < CHUNK; ++l) {
        const float* cr = cr0 + l * CSTR;   // block-uniform -> s_load
        float g = gt[l];
        float v = vbuf[l];
        float vg = v * g;
        #pragma unroll
        for (int q = 0; q < 9; ++q) {
            float val = (q <= 4) ? vg : v;   // planes 0-19 gated, 20-35 ungated
            #pragma unroll
            for (int j = 0; j < 4; ++j) {
                sre[4*q+j] += cr[4*q+j] * val;
                sim[4*q+j] += cr[36 + 4*q+j] * val;
            }
        }
    }
    size_t base = ((size_t)(b * NC + c) * 72) * DDIM + d;
    #pragma unroll
    for (int i = 0; i < 36; ++i) {
        S[base + (size_t)i * DDIM] = sre[i];
        S[base + (size_t)(36 + i) * DDIM] = sim[i];
    }
}

// ---------------- K5b: exclusive prefix over chunks (register-batched) ----------------
__global__ void k_prefix(float* __restrict__ S) {
    int q = blockIdx.x, b = blockIdx.z, d = blockIdx.y * 64 + threadIdx.x;
    float acc = 0.f;
    for (int batch = 0; batch < NC / 32; ++batch) {
        float r[32];
        #pragma unroll
        for (int i = 0; i < 32; ++i)
            r[i] = S[((size_t)(b * NC + batch * 32 + i) * 72 + q) * DDIM + d];
        #pragma unroll
        for (int i = 0; i < 32; ++i) { float tmp = r[i]; r[i] = acc; acc += tmp; }
        #pragma unroll
        for (int i = 0; i < 32; ++i)
            S[((size_t)(b * NC + batch * 32 + i) * 72 + q) * DDIM + d] = r[i];
    }
}

// ---------------- K5c: within-chunk scan + retrieval (+0.125*pers, in place) ----------------
__global__ void k_scan(const float* __restrict__ coef, const float* __restrict__ V,
                       const float* __restrict__ gate, const float* __restrict__ S,
                       float* __restrict__ tp) {
    int c = blockIdx.x, b = blockIdx.z, d = blockIdx.y * 64 + threadIdx.x;
    const float* cr0 = coef + ((size_t)(b * LSEQ + c * CHUNK)) * CSTR;
    const float* gt  = gate + b * LSEQ + c * CHUNK;
    float vbuf[CHUNK], tpb[CHUNK];
    #pragma unroll
    for (int l = 0; l < CHUNK; ++l) {
        size_t idx = ((size_t)(b * LSEQ + c * CHUNK + l)) * DDIM + d;
        vbuf[l] = V[idx];
        tpb[l]  = tp[idx];
    }
    float sre[36], sim[36];
    size_t base = ((size_t)(b * NC + c) * 72) * DDIM + d;
    #pragma unroll
    for (int i = 0; i < 36; ++i) {
        sre[i] = S[base + (size_t)i * DDIM];
        sim[i] = S[base + (size_t)(36 + i) * DDIM];
    }
    #pragma unroll
    for (int l = 0; l < CHUNK; ++l) {
        const float* cr = cr0 + l * CSTR;   // block-uniform -> s_load
        float g = gt[l];
        float v = vbuf[l];
        float vg = v * g;
        float rx = 0.f, ry = 0.f, rz = 0.f, rw = 0.f;
        #pragma unroll
        for (int q = 0; q < 9; ++q) {
            float val = (q <= 4) ? vg : v;
            sre[4*q+0] += cr[4*q+0] * val; rx += cr[72+4*q+0] * sre[4*q+0];
            sre[4*q+1] += cr[4*q+1] * val; ry += cr[72+4*q+1] * sre[4*q+1];
            sre[4*q+2] += cr[4*q+2] * val; rz += cr[72+4*q+2] * sre[4*q+2];
            sre[4*q+3] += cr[4*q+3] * val; rw += cr[72+4*q+3] * sre[4*q+3];
            sim[4*q+0] += cr[36+4*q+0] * val; rx += cr[108+4*q+0] * sim[4*q+0];
            sim[4*q+1] += cr[36+4*q+1] * val; ry += cr[108+4*q+1] * sim[4*q+1];
            sim[4*q+2] += cr[36+4*q+2] * val; rz += cr[108+4*q+2] * sim[4*q+2];
            sim[4*q+3] += cr[36+4*q+3] * val; rw += cr[108+4*q+3] * sim[4*q+3];
        }
        size_t oidx = ((size_t)(b * LSEQ + c * CHUNK + l)) * DDIM + d;
        tp[oidx] = ((rx + ry) + (rz + rw)) + 0.125f * tpb[l];  // tp aliases pers
    }
}

// ---------------- K6: epilogue: (total/norm) @ out_proj + x (2-row tile) ----------------
__global__ void k_out(const float* __restrict__ x, const float* __restrict__ tp,
                      const float* __restrict__ op, float* __restrict__ out) {
    int r0 = blockIdx.x * ROWS;
    int t = threadIdx.x;
    __shared__ __align__(16) float ts[ROWS][DDIM];
    #pragma unroll
    for (int r = 0; r < ROWS; ++r) {
        int l = (r0 + r) & (LSEQ - 1);
        float invn = 1.0f / (2.0f * sqrtf((float)(l + 1)));
        ts[r][t] = tp[(size_t)(r0 + r) * DDIM + t] * invn;
    }
    __syncthreads();
    float a0 = 0.f, a1 = 0.f;
    const float4* t40 = (const float4*)&ts[0][0];
    const float4* t41 = (const float4*)&ts[1][0];
    #pragma unroll 4
    for (int i4 = 0; i4 < DDIM / 4; ++i4) {
        float4 v0 = t40[i4], v1 = t41[i4];
        float w0 = op[(4*i4+0) * DDIM + t];
        float w1 = op[(4*i4+1) * DDIM + t];
        float w2 = op[(4*i4+2) * DDIM + t];
        float w3 = op[(4*i4+3) * DDIM + t];
        a0 += v0.x * w0 + v0.y * w1 + v0.z * w2 + v0.w * w3;
        a1 += v1.x * w0 + v1.y * w1 + v1.z * w2 + v1.w * w3;
    }
    out[(size_t)(r0 + 0) * DDIM + t] = x[(size_t)(r0 + 0) * DDIM + t] + a0;
    out[(size_t)(r0 + 1) * DDIM + t] = x[(size_t)(r0 + 1) * DDIM + t] + a1;
}

extern "C" void kernel_launch(void* const* d_in, const int* in_sizes, int n_in,
                              void* d_out, int out_size, void* d_ws, size_t ws_size,
                              hipStream_t stream) {
    const float* x   = (const float*)d_in[0];
    const float* kp  = (const float*)d_in[1];
    const float* qp  = (const float*)d_in[2];
    const float* vp  = (const float*)d_in[3];
    const float* op  = (const float*)d_in[4];
    const float* lkp = (const float*)d_in[5];
    const float* pf  = (const float*)d_in[7];
    const float* bre = (const float*)d_in[10];
    const float* bim = (const float*)d_in[11];
    float* out = (float*)d_out;

    const int B = 2;
    float* w = (float*)d_ws;
    size_t off = 0;
    float* coef  = w + off; off += (size_t)B * LSEQ * CSTR;
    float* V     = w + off; off += (size_t)B * LSEQ * DDIM;
    float* pers  = w + off; off += (size_t)B * LSEQ * DDIM;       // aliased as tcp
    float* gate  = w + off; off += (size_t)B * LSEQ;
    float* Ssum  = w + off; off += (size_t)B * NCS * DDIM;
    float* Ssq   = w + off; off += (size_t)B * NCS * DDIM;
    // X region: rmean+rstd (dead after k_ltm) aliased with S (written by k_chunksum)
    float* rmean = w + off;
    float* rstd  = w + off + (size_t)B * LSEQ * DDIM;
    float* S     = w + off; off += (size_t)B * NC * 72 * DDIM;

    k_phases<<<dim3(B * LSEQ / ROWS), dim3(256), 0, stream>>>(x, kp, qp, vp, pf, coef, V);
    k_gate<<<dim3(B), dim3(256), 0, stream>>>(coef, gate);
    k_stats1<<<dim3(NCS, 4, B), dim3(64), 0, stream>>>(x, Ssum, Ssq);
    k_stats2<<<dim3(NCS, 4, B), dim3(64), 0, stream>>>(x, Ssum, Ssq, rmean, rstd);
    k_ltm<<<dim3(B * LSEQ / ROWS), dim3(256), 0, stream>>>(x, rmean, rstd, lkp, bre, bim, pers);
    k_chunksum<<<dim3(NC, 4, B), dim3(64), 0, stream>>>(coef, V, gate, S);
    k_prefix<<<dim3(72, 4, B), dim3(64), 0, stream>>>(S);
    k_scan<<<dim3(NC, 4, B), dim3(64), 0, stream>>>(coef, V, gate, S, pers);
    k_out<<<dim3(B * LSEQ / ROWS), dim3(256), 0, stream>>>(x, pers, op, out);
}